// Round 3
// baseline (852.403 us; speedup 1.0000x reference)
//
#include <hip/hip_runtime.h>
#include <math.h>

#define B   2
#define H   192
#define W   320
#define HW  (H * W)
#define BHW (B * HW)
#define CTX 195

// output offsets (in floats), concatenated in reference return order
#define OFS_CUR   0
#define OFS_REF0  (3 * BHW)
#define OFS_REF2  (6 * BHW)
#define OFS_CTX0  (9 * BHW)
#define OFS_CTX2  (9 * BHW + CTX * BHW)
#define OFS_OFF0  (9 * BHW + 2 * CTX * BHW)
#define OFS_OFF1  (OFS_OFF0 + 2 * BHW)

#define NCH   99
#define NGRP  2     // 198 channels (3 im + 195 ctx) = NCH * NGRP
#define TX    32
#define TY    8
#define NTX   (W / TX)          // 10
#define NTY   (H / TY)          // 24
#define NTILE (NTX * NTY * B)   // 480
#define NBLK  (NTILE * NGRP * 2) // 1920, divisible by 8

typedef float f4a __attribute__((ext_vector_type(4), aligned(4)));

__device__ __forceinline__ int iclip(int v, int lo, int hi) {
    return v < lo ? lo : (v > hi ? hi : v);
}

// Forward splat: acc += -flow * d at 4 integer neighbors of (x+fx, y+fy); cnt += d.
__global__ __launch_bounds__(256) void splat_kernel(
    const float* __restrict__ flow0, const float* __restrict__ flow1,
    const float* __restrict__ dep0,  const float* __restrict__ dep1,
    float* __restrict__ out, float* __restrict__ cnt)
{
    int tid = blockIdx.x * blockDim.x + threadIdx.x;
    if (tid >= 2 * BHW) return;
    int s   = tid / BHW;
    int p   = tid - s * BHW;
    int b   = p / HW;
    int pix = p - b * HW;
    int y   = pix / W;
    int x   = pix - y * W;

    const float* flow = s ? flow1 : flow0;
    const float* dep  = s ? dep1  : dep0;
    float fx = flow[(b * 2 + 0) * HW + pix];
    float fy = flow[(b * 2 + 1) * HW + pix];
    float d  = dep[b * HW + pix];

    int xL = (int)floorf((float)x + fx);
    int yT = (int)floorf((float)y + fy);

    float* acc = out + (s ? OFS_OFF1 : OFS_OFF0) + b * 2 * HW;
    float* cn  = cnt + s * BHW + b * HW;

    float wx = -fx * d;
    float wy = -fy * d;
    #pragma unroll
    for (int dy = 0; dy < 2; dy++) {
        #pragma unroll
        for (int dx = 0; dx < 2; dx++) {
            int xi = xL + dx;
            int yi = yT + dy;
            if (xi >= 0 && xi < W && yi >= 0 && yi < H) {
                int q = yi * W + xi;
                atomicAdd(&acc[q],      wx);
                atomicAdd(&acc[HW + q], wy);
                atomicAdd(&cn[q],       d);
            }
        }
    }
}

// Normalize splat: off = acc / cnt where cnt > 0 else 0.
__global__ __launch_bounds__(256) void norm_kernel(
    float* __restrict__ out, const float* __restrict__ cnt)
{
    int tid = blockIdx.x * blockDim.x + threadIdx.x;
    if (tid >= 2 * BHW) return;
    int s   = tid / BHW;
    int p   = tid - s * BHW;
    int b   = p / HW;
    int pix = p - b * HW;

    float c = cnt[s * BHW + b * HW + pix];
    float* acc = out + (s ? OFS_OFF1 : OFS_OFF0) + b * 2 * HW;
    if (c > 0.0f) {
        acc[pix]      = acc[pix] / c;
        acc[HW + pix] = acc[HW + pix] / c;
    } else {
        acc[pix]      = 0.0f;
        acc[HW + pix] = 0.0f;
    }
}

// interior channel body: 5 rows x (dwordx4 + dword), 25 FMA with merged 5x5 weights
#define VBODY(PLANE, STORE)                                            \
    {                                                                  \
        const float* p0 = (PLANE) + base;                              \
        float acc = 0.0f;                                              \
        _Pragma("unroll")                                              \
        for (int r = 0; r < 5; r++) {                                  \
            const float* row = p0 + r * W;                             \
            f4a v0 = *(const f4a*)row;                                 \
            float v4 = row[4];                                         \
            acc = fmaf(mw[r][0], v0.x, acc);                           \
            acc = fmaf(mw[r][1], v0.y, acc);                           \
            acc = fmaf(mw[r][2], v0.z, acc);                           \
            acc = fmaf(mw[r][3], v0.w, acc);                           \
            acc = fmaf(mw[r][4], v4,   acc);                           \
        }                                                              \
        STORE;                                                         \
    }

// exact border channel body: per-tap independent clipping
#define BBODY(PLANE, STORE)                                            \
    {                                                                  \
        const float* plane = (PLANE);                                  \
        float acc = 0.0f;                                              \
        _Pragma("unroll")                                              \
        for (int fj = 0; fj < 4; fj++) {                               \
            const float* rT = plane + yi[fj]  * W;                     \
            const float* rB = plane + yi1[fj] * W;                     \
            _Pragma("unroll")                                          \
            for (int fi = 0; fi < 4; fi++) {                           \
                float samp = a00 * rT[xi[fi]] + a10 * rT[xi1[fi]]      \
                           + a01 * rB[xi[fi]] + a11 * rB[xi1[fi]];     \
                acc = fmaf(fw[fj * 4 + fi], samp, acc);                \
            }                                                          \
        }                                                              \
        STORE;                                                         \
    }

// Per-pixel 4x4 adaptive filter bilinearly sampled at (x2+fi-1, y2+fj-1).
// 2D-tiled pixels + XCD-swizzled blocks + merged 5x5 interior stencil.
__global__ __launch_bounds__(256) void interp_kernel(
    const float* __restrict__ im0,   const float* __restrict__ im2,
    const float* __restrict__ ctx0,  const float* __restrict__ ctx2,
    const float* __restrict__ filt0, const float* __restrict__ filt1,
    float* __restrict__ out)
{
    // XCD-aware swizzle: adjacent tiles -> same XCD (NBLK % 8 == 0)
    int lin = blockIdx.x + NTILE * (blockIdx.y + NGRP * blockIdx.z);
    int newlin = (lin & 7) * (NBLK / 8) + (lin >> 3);
    int tile = newlin % NTILE;
    int rest = newlin / NTILE;
    int g = rest % NGRP;
    int s = rest / NGRP;
    int b  = tile / (NTX * NTY);
    int t2 = tile % (NTX * NTY);
    int x = (t2 % NTX) * TX + ((int)threadIdx.x % TX);
    int y = (t2 / NTX) * TY + ((int)threadIdx.x / TX);
    int pix = y * W + x;

    const float* off = out + (s ? OFS_OFF1 : OFS_OFF0) + b * 2 * HW;
    float ox = off[pix];
    float oy = off[HW + pix];
    float x2 = (float)x + ox;
    float y2 = (float)y + oy;

    bool valid = (x2 >= 0.0f) && (x2 <= (float)(W - 1)) &&
                 (y2 >= 0.0f) && (y2 <= (float)(H - 1));

    const float* imsrc  = s ? im2  : im0;
    const float* ctxsrc = s ? ctx2 : ctx0;
    float* oim  = out + (s ? OFS_REF2 : OFS_REF0) + b * 3 * HW + pix;
    float* octx = out + (s ? OFS_CTX2 : OFS_CTX0) + b * CTX * HW + pix;

    int c0 = g * NCH, c1 = c0 + NCH;
    int imEnd  = c1 < 3 ? c1 : 3;      // im channels in [c0, imEnd)
    int ctxBeg = c0 > 3 ? c0 : 3;      // ctx channels in [ctxBeg, c1)

    if (!valid) {
        for (int c = c0; c < imEnd; c++) oim[c * HW] = 0.0f;
        for (int c = ctxBeg; c < c1; c++)
            __builtin_nontemporal_store(0.0f, &octx[(c - 3) * HW]);
        return;
    }

    float xLf = floorf(x2), yTf = floorf(y2);
    float alpha = x2 - xLf, beta = y2 - yTf;
    int xL = (int)xLf, yT = (int)yTf;

    const float* filt = (s ? filt1 : filt0) + b * 16 * HW + pix;
    float fw[16];
    #pragma unroll
    for (int t = 0; t < 16; t++)
        fw[t] = __builtin_nontemporal_load(&filt[t * HW]);

    float a00 = (1.0f - alpha) * (1.0f - beta);
    float a10 = alpha * (1.0f - beta);
    float a01 = (1.0f - alpha) * beta;
    float a11 = alpha * beta;

    bool interior = (xL >= 1) && (xL <= W - 4) && (yT >= 1) && (yT <= H - 4);

    if (interior) {
        // merged 5x5 stencil: correlation of F with the bilinear kernel
        float mw[5][5];
        #pragma unroll
        for (int r = 0; r < 5; r++) {
            #pragma unroll
            for (int c = 0; c < 5; c++) {
                float v = 0.0f;
                if (r < 4 && c < 4)   v += a00 * fw[r * 4 + c];
                if (r < 4 && c >= 1)  v += a10 * fw[r * 4 + c - 1];
                if (r >= 1 && c < 4)  v += a01 * fw[(r - 1) * 4 + c];
                if (r >= 1 && c >= 1) v += a11 * fw[(r - 1) * 4 + c - 1];
                mw[r][c] = v;
            }
        }
        int base = (yT - 1) * W + (xL - 1);
        for (int c = c0; c < imEnd; c++)
            VBODY(imsrc + (b * 3 + c) * HW, oim[c * HW] = acc)
        for (int c = ctxBeg; c < c1; c++)
            VBODY(ctxsrc + (b * CTX + (c - 3)) * HW,
                  __builtin_nontemporal_store(acc, &octx[(c - 3) * HW]))
    } else {
        int xi[4], xi1[4], yi[4], yi1[4];
        #pragma unroll
        for (int f = 0; f < 4; f++) {
            int a = iclip(xL + f - 1, 0, W - 1);
            xi[f]  = a;
            xi1[f] = a + 1 > W - 1 ? W - 1 : a + 1;
            int bb = iclip(yT + f - 1, 0, H - 1);
            yi[f]  = bb;
            yi1[f] = bb + 1 > H - 1 ? H - 1 : bb + 1;
        }
        for (int c = c0; c < imEnd; c++)
            BBODY(imsrc + (b * 3 + c) * HW, oim[c * HW] = acc)
        for (int c = ctxBeg; c < c1; c++)
            BBODY(ctxsrc + (b * CTX + (c - 3)) * HW,
                  __builtin_nontemporal_store(acc, &octx[(c - 3) * HW]))
    }
}

__global__ __launch_bounds__(256) void cur_kernel(float* __restrict__ out)
{
    int i = blockIdx.x * blockDim.x + threadIdx.x;
    if (i < 3 * BHW)
        out[OFS_CUR + i] = 0.5f * (out[OFS_REF0 + i] + out[OFS_REF2 + i]);
}

extern "C" void kernel_launch(void* const* d_in, const int* in_sizes, int n_in,
                              void* d_out, int out_size, void* d_ws, size_t ws_size,
                              hipStream_t stream)
{
    const float* im0    = (const float*)d_in[0];
    const float* im2    = (const float*)d_in[1];
    const float* ctx0   = (const float*)d_in[2];
    const float* ctx2   = (const float*)d_in[3];
    const float* flow01 = (const float*)d_in[4];
    const float* flow10 = (const float*)d_in[5];
    const float* dep0   = (const float*)d_in[6];
    const float* dep1   = (const float*)d_in[7];
    const float* filt0  = (const float*)d_in[8];
    const float* filt1  = (const float*)d_in[9];

    float* out = (float*)d_out;
    float* cnt = (float*)d_ws;   // 2*BHW floats

    hipMemsetAsync(out + OFS_OFF0, 0, (size_t)(4 * BHW) * sizeof(float), stream);
    hipMemsetAsync(cnt, 0, (size_t)(2 * BHW) * sizeof(float), stream);

    dim3 blk(256);
    splat_kernel<<<dim3((2 * BHW + 255) / 256), blk, 0, stream>>>(
        flow01, flow10, dep0, dep1, out, cnt);
    norm_kernel<<<dim3((2 * BHW + 255) / 256), blk, 0, stream>>>(out, cnt);

    dim3 igrid(NTILE, NGRP, 2);
    interp_kernel<<<igrid, blk, 0, stream>>>(im0, im2, ctx0, ctx2, filt0, filt1, out);

    cur_kernel<<<dim3((3 * BHW + 255) / 256), blk, 0, stream>>>(out);
}

// Round 4
// 712.274 us; speedup vs baseline: 1.1967x; 1.1967x over previous
//
#include <hip/hip_runtime.h>
#include <math.h>

#define B   2
#define H   192
#define W   320
#define HW  (H * W)
#define BHW (B * HW)
#define CTX 195

// output offsets (in floats), concatenated in reference return order
#define OFS_CUR   0
#define OFS_REF0  (3 * BHW)
#define OFS_REF2  (6 * BHW)
#define OFS_CTX0  (9 * BHW)
#define OFS_CTX2  (9 * BHW + CTX * BHW)
#define OFS_OFF0  (9 * BHW + 2 * CTX * BHW)
#define OFS_OFF1  (OFS_OFF0 + 2 * BHW)

#define NCH   33
#define NGRP  6     // 198 channels (3 im + 195 ctx) = NCH * NGRP
#define TX    32
#define TY    8
#define NTX   (W / TX)          // 10
#define NTY   (H / TY)          // 24
#define NTILE (NTX * NTY * B)   // 480
#define NBLK  (NTILE * NGRP * 2) // 5760, divisible by 8

typedef float f4a __attribute__((ext_vector_type(4), aligned(4)));

__device__ __forceinline__ int iclip(int v, int lo, int hi) {
    return v < lo ? lo : (v > hi ? hi : v);
}

// Forward splat: acc += -flow * d at 4 integer neighbors of (x+fx, y+fy); cnt += d.
__global__ __launch_bounds__(256) void splat_kernel(
    const float* __restrict__ flow0, const float* __restrict__ flow1,
    const float* __restrict__ dep0,  const float* __restrict__ dep1,
    float* __restrict__ out, float* __restrict__ cnt)
{
    int tid = blockIdx.x * blockDim.x + threadIdx.x;
    if (tid >= 2 * BHW) return;
    int s   = tid / BHW;
    int p   = tid - s * BHW;
    int b   = p / HW;
    int pix = p - b * HW;
    int y   = pix / W;
    int x   = pix - y * W;

    const float* flow = s ? flow1 : flow0;
    const float* dep  = s ? dep1  : dep0;
    float fx = flow[(b * 2 + 0) * HW + pix];
    float fy = flow[(b * 2 + 1) * HW + pix];
    float d  = dep[b * HW + pix];

    int xL = (int)floorf((float)x + fx);
    int yT = (int)floorf((float)y + fy);

    float* acc = out + (s ? OFS_OFF1 : OFS_OFF0) + b * 2 * HW;
    float* cn  = cnt + s * BHW + b * HW;

    float wx = -fx * d;
    float wy = -fy * d;
    #pragma unroll
    for (int dy = 0; dy < 2; dy++) {
        #pragma unroll
        for (int dx = 0; dx < 2; dx++) {
            int xi = xL + dx;
            int yi = yT + dy;
            if (xi >= 0 && xi < W && yi >= 0 && yi < H) {
                int q = yi * W + xi;
                atomicAdd(&acc[q],      wx);
                atomicAdd(&acc[HW + q], wy);
                atomicAdd(&cn[q],       d);
            }
        }
    }
}

// Normalize splat: off = acc / cnt where cnt > 0 else 0.
__global__ __launch_bounds__(256) void norm_kernel(
    float* __restrict__ out, const float* __restrict__ cnt)
{
    int tid = blockIdx.x * blockDim.x + threadIdx.x;
    if (tid >= 2 * BHW) return;
    int s   = tid / BHW;
    int p   = tid - s * BHW;
    int b   = p / HW;
    int pix = p - b * HW;

    float c = cnt[s * BHW + b * HW + pix];
    float* acc = out + (s ? OFS_OFF1 : OFS_OFF0) + b * 2 * HW;
    if (c > 0.0f) {
        acc[pix]      = acc[pix] / c;
        acc[HW + pix] = acc[HW + pix] / c;
    } else {
        acc[pix]      = 0.0f;
        acc[HW + pix] = 0.0f;
    }
}

// interior channel body: 5 rows x (dwordx4 + dword), 25 FMA with merged 5x5 weights
#define VBODY(PLANE, STORE)                                            \
    {                                                                  \
        const float* p0 = (PLANE) + base;                              \
        float acc = 0.0f;                                              \
        _Pragma("unroll")                                              \
        for (int r = 0; r < 5; r++) {                                  \
            const float* row = p0 + r * W;                             \
            f4a v0 = *(const f4a*)row;                                 \
            float v4 = row[4];                                         \
            acc = fmaf(mw[r][0], v0.x, acc);                           \
            acc = fmaf(mw[r][1], v0.y, acc);                           \
            acc = fmaf(mw[r][2], v0.z, acc);                           \
            acc = fmaf(mw[r][3], v0.w, acc);                           \
            acc = fmaf(mw[r][4], v4,   acc);                           \
        }                                                              \
        STORE;                                                         \
    }

// exact border channel body: per-tap independent clipping
#define BBODY(PLANE, STORE)                                            \
    {                                                                  \
        const float* plane = (PLANE);                                  \
        float acc = 0.0f;                                              \
        _Pragma("unroll")                                              \
        for (int fj = 0; fj < 4; fj++) {                               \
            const float* rT = plane + yi[fj]  * W;                     \
            const float* rB = plane + yi1[fj] * W;                     \
            _Pragma("unroll")                                          \
            for (int fi = 0; fi < 4; fi++) {                           \
                float samp = a00 * rT[xi[fi]] + a10 * rT[xi1[fi]]      \
                           + a01 * rB[xi[fi]] + a11 * rB[xi1[fi]];     \
                acc = fmaf(fw[fj * 4 + fi], samp, acc);                \
            }                                                          \
        }                                                              \
        STORE;                                                         \
    }

// Per-pixel 4x4 adaptive filter bilinearly sampled at (x2+fi-1, y2+fj-1).
// 2D-tiled pixels + XCD-swizzled blocks + merged 5x5 interior stencil.
__global__ __launch_bounds__(256) void interp_kernel(
    const float* __restrict__ im0,   const float* __restrict__ im2,
    const float* __restrict__ ctx0,  const float* __restrict__ ctx2,
    const float* __restrict__ filt0, const float* __restrict__ filt1,
    float* __restrict__ out)
{
    // XCD-aware swizzle: each XCD gets a contiguous chunk of work (NBLK % 8 == 0)
    int lin = blockIdx.x + NTILE * (blockIdx.y + NGRP * blockIdx.z);
    int newlin = (lin & 7) * (NBLK / 8) + (lin >> 3);
    int tile = newlin % NTILE;
    int rest = newlin / NTILE;
    int g = rest % NGRP;
    int s = rest / NGRP;
    int b  = tile / (NTX * NTY);
    int t2 = tile % (NTX * NTY);
    int x = (t2 % NTX) * TX + ((int)threadIdx.x % TX);
    int y = (t2 / NTX) * TY + ((int)threadIdx.x / TX);
    int pix = y * W + x;

    const float* off = out + (s ? OFS_OFF1 : OFS_OFF0) + b * 2 * HW;
    float ox = off[pix];
    float oy = off[HW + pix];
    float x2 = (float)x + ox;
    float y2 = (float)y + oy;

    bool valid = (x2 >= 0.0f) && (x2 <= (float)(W - 1)) &&
                 (y2 >= 0.0f) && (y2 <= (float)(H - 1));

    const float* imsrc  = s ? im2  : im0;
    const float* ctxsrc = s ? ctx2 : ctx0;
    float* oim  = out + (s ? OFS_REF2 : OFS_REF0) + b * 3 * HW + pix;
    float* octx = out + (s ? OFS_CTX2 : OFS_CTX0) + b * CTX * HW + pix;

    int c0 = g * NCH, c1 = c0 + NCH;
    int imEnd  = c1 < 3 ? c1 : 3;      // im channels in [c0, imEnd)
    int ctxBeg = c0 > 3 ? c0 : 3;      // ctx channels in [ctxBeg, c1)

    if (!valid) {
        for (int c = c0; c < imEnd; c++) oim[c * HW] = 0.0f;
        for (int c = ctxBeg; c < c1; c++)
            __builtin_nontemporal_store(0.0f, &octx[(c - 3) * HW]);
        return;
    }

    float xLf = floorf(x2), yTf = floorf(y2);
    float alpha = x2 - xLf, beta = y2 - yTf;
    int xL = (int)xLf, yT = (int)yTf;

    const float* filt = (s ? filt1 : filt0) + b * 16 * HW + pix;
    float fw[16];
    #pragma unroll
    for (int t = 0; t < 16; t++) fw[t] = filt[t * HW];

    float a00 = (1.0f - alpha) * (1.0f - beta);
    float a10 = alpha * (1.0f - beta);
    float a01 = (1.0f - alpha) * beta;
    float a11 = alpha * beta;

    bool interior = (xL >= 1) && (xL <= W - 4) && (yT >= 1) && (yT <= H - 4);

    if (interior) {
        // merged 5x5 stencil: correlation of F with the bilinear kernel
        float mw[5][5];
        #pragma unroll
        for (int r = 0; r < 5; r++) {
            #pragma unroll
            for (int c = 0; c < 5; c++) {
                float v = 0.0f;
                if (r < 4 && c < 4)   v += a00 * fw[r * 4 + c];
                if (r < 4 && c >= 1)  v += a10 * fw[r * 4 + c - 1];
                if (r >= 1 && c < 4)  v += a01 * fw[(r - 1) * 4 + c];
                if (r >= 1 && c >= 1) v += a11 * fw[(r - 1) * 4 + c - 1];
                mw[r][c] = v;
            }
        }
        int base = (yT - 1) * W + (xL - 1);
        for (int c = c0; c < imEnd; c++)
            VBODY(imsrc + (b * 3 + c) * HW, oim[c * HW] = acc)
        #pragma unroll 2
        for (int c = ctxBeg; c < c1; c++)
            VBODY(ctxsrc + (b * CTX + (c - 3)) * HW,
                  __builtin_nontemporal_store(acc, &octx[(c - 3) * HW]))
    } else {
        int xi[4], xi1[4], yi[4], yi1[4];
        #pragma unroll
        for (int f = 0; f < 4; f++) {
            int a = iclip(xL + f - 1, 0, W - 1);
            xi[f]  = a;
            xi1[f] = a + 1 > W - 1 ? W - 1 : a + 1;
            int bb = iclip(yT + f - 1, 0, H - 1);
            yi[f]  = bb;
            yi1[f] = bb + 1 > H - 1 ? H - 1 : bb + 1;
        }
        for (int c = c0; c < imEnd; c++)
            BBODY(imsrc + (b * 3 + c) * HW, oim[c * HW] = acc)
        for (int c = ctxBeg; c < c1; c++)
            BBODY(ctxsrc + (b * CTX + (c - 3)) * HW,
                  __builtin_nontemporal_store(acc, &octx[(c - 3) * HW]))
    }
}

__global__ __launch_bounds__(256) void cur_kernel(float* __restrict__ out)
{
    int i = blockIdx.x * blockDim.x + threadIdx.x;
    if (i < 3 * BHW)
        out[OFS_CUR + i] = 0.5f * (out[OFS_REF0 + i] + out[OFS_REF2 + i]);
}

extern "C" void kernel_launch(void* const* d_in, const int* in_sizes, int n_in,
                              void* d_out, int out_size, void* d_ws, size_t ws_size,
                              hipStream_t stream)
{
    const float* im0    = (const float*)d_in[0];
    const float* im2    = (const float*)d_in[1];
    const float* ctx0   = (const float*)d_in[2];
    const float* ctx2   = (const float*)d_in[3];
    const float* flow01 = (const float*)d_in[4];
    const float* flow10 = (const float*)d_in[5];
    const float* dep0   = (const float*)d_in[6];
    const float* dep1   = (const float*)d_in[7];
    const float* filt0  = (const float*)d_in[8];
    const float* filt1  = (const float*)d_in[9];

    float* out = (float*)d_out;
    float* cnt = (float*)d_ws;   // 2*BHW floats

    hipMemsetAsync(out + OFS_OFF0, 0, (size_t)(4 * BHW) * sizeof(float), stream);
    hipMemsetAsync(cnt, 0, (size_t)(2 * BHW) * sizeof(float), stream);

    dim3 blk(256);
    splat_kernel<<<dim3((2 * BHW + 255) / 256), blk, 0, stream>>>(
        flow01, flow10, dep0, dep1, out, cnt);
    norm_kernel<<<dim3((2 * BHW + 255) / 256), blk, 0, stream>>>(out, cnt);

    dim3 igrid(NTILE, NGRP, 2);
    interp_kernel<<<igrid, blk, 0, stream>>>(im0, im2, ctx0, ctx2, filt0, filt1, out);

    cur_kernel<<<dim3((3 * BHW + 255) / 256), blk, 0, stream>>>(out);
}